// Round 9
// baseline (140.337 us; speedup 1.0000x reference)
//
#include <hip/hip_runtime.h>

#define M_ROWS 1024
#define DIM 512
#define NB 1024              // row bytes = DIM*2
#define N_TOT 7168           // M + 2*M*C
#define TEXT_OFF 1024
#define SHUF_OFF 4096
#define INV_T (1.0f/0.07f)
#define MARGIN_V 0.2f
#define TILES2 28            // N_TOT / 256
#define NBLK2 406            // 28*29/2 upper-triangular 256^2 tiles
#define SLOT 1536            // floats per partial slot: [2 sides][3 vals][256 rows]

typedef __attribute__((ext_vector_type(8))) short bf16x8;
typedef __attribute__((ext_vector_type(4))) float f32x4;

__device__ __forceinline__ ushort f2bf(float f) {
  unsigned u = __float_as_uint(f);
  u += 0x7fffu + ((u >> 16) & 1u);   // RTNE
  return (ushort)(u >> 16);
}

// ------- Kernel 1: normalize + cast bf16 + build ids -------
__global__ __launch_bounds__(256) void k_normalize(
    const float* __restrict__ motion, const float* __restrict__ text,
    const float* __restrict__ shuf, const int* __restrict__ mids,
    ushort* __restrict__ emb, int* __restrict__ ids) {
  int wave = threadIdx.x >> 6;
  int lane = threadIdx.x & 63;
  int row = blockIdx.x * 4 + wave;
  if (row >= N_TOT) return;
  const float* src;
  int id;
  if (row < TEXT_OFF) { src = motion + (size_t)row * DIM; id = mids[row]; }
  else if (row < SHUF_OFF) { int r = row - TEXT_OFF; src = text + (size_t)r * DIM; id = mids[r / 3]; }
  else { int r = row - SHUF_OFF; src = shuf + (size_t)r * DIM; id = mids[r / 3] + 100000; }

  float4 a = ((const float4*)src)[lane * 2];
  float4 b = ((const float4*)src)[lane * 2 + 1];
  float v0 = a.x + 1e-8f, v1 = a.y + 1e-8f, v2 = a.z + 1e-8f, v3 = a.w + 1e-8f;
  float v4 = b.x + 1e-8f, v5 = b.y + 1e-8f, v6 = b.z + 1e-8f, v7 = b.w + 1e-8f;
  float ss = v0*v0 + v1*v1 + v2*v2 + v3*v3 + v4*v4 + v5*v5 + v6*v6 + v7*v7;
  #pragma unroll
  for (int m = 1; m < 64; m <<= 1) ss += __shfl_xor(ss, m);
  float inv = 1.0f / fmaxf(sqrtf(ss), 1e-12f);

  uint w0 = (uint)f2bf(v0 * inv) | ((uint)f2bf(v1 * inv) << 16);
  uint w1 = (uint)f2bf(v2 * inv) | ((uint)f2bf(v3 * inv) << 16);
  uint w2 = (uint)f2bf(v4 * inv) | ((uint)f2bf(v5 * inv) << 16);
  uint w3 = (uint)f2bf(v6 * inv) | ((uint)f2bf(v7 * inv) << 16);
  uint4 pk; pk.x = w0; pk.y = w1; pk.z = w2; pk.w = w3;
  *((uint4*)(emb + (size_t)row * DIM + lane * 8)) = pk;
  if (lane == 0) ids[row] = id;
}

// -------- Kernel 2: symmetric fused A*A^T, 256^2 tiles, 8 waves --------
// DIRECT register loading: MFMA fragments are loaded straight from global
// (L1/L2-resident; a wave's fragment load touches the same 16x64B lines a
// fully-coalesced load would). NO LDS staging, NO barriers in the K-loop:
// 8 waves free-run and hide each other's memory latency.
// No global atomics: partials to private slots, k_reduce sums them.
__global__ __launch_bounds__(512, 2) void k_gemm_loss(
    const ushort* __restrict__ emb, const int* __restrict__ ids,
    float* __restrict__ part) {
  __shared__ float rpd[1024];   // row-partial exchange: [8 waves][128 rows]
  __shared__ float rpp[1024];
  __shared__ float rpm[1024];
  __shared__ float cps[1536];   // col-partial exchange
  __shared__ int ridL[256];
  __shared__ int cidL[256];

  // bijective XCD-chunked swizzle: nwg=406, q=50, r=6
  int orig = blockIdx.x;
  int xcd = orig & 7;
  int idx = orig >> 3;
  int bid = (xcd < 6 ? xcd * 51 : 306 + (xcd - 6) * 50) + idx;

  // triangular tile decode: bid -> (x, y), x <= y
  int x = 0;
  while (bid >= TILES2 - x) { bid -= TILES2 - x; x++; }
  int y = x + bid;
  bool diag = (x == y);
  int brow = x * 256, bcol = y * 256;
  int tbid = x * TILES2 - x * (x - 1) / 2 + (y - x);   // linear triangular id

  int t = threadIdx.x;
  int l = t & 63;
  int w = t >> 6;
  int wr = w >> 2;           // wave row 0..1  -> 128 output rows
  int wc = w & 3;            // wave col 0..3  -> 64 output cols
  int fr = l & 15;
  int fg = l >> 4;           // 0..3

  if (t < 256) ridL[t] = ids[brow + t];
  else if (t < 512) cidL[t - 256] = ids[bcol + (t - 256)];

  f32x4 acc[8][4];
  #pragma unroll
  for (int m = 0; m < 8; m++)
    #pragma unroll
    for (int n = 0; n < 4; n++)
      acc[m][n] = (f32x4){0.f, 0.f, 0.f, 0.f};

  // per-lane fragment base pointers (16 B per lane; fg groups cover 64 B line)
  const char* pa = (const char*)emb + (size_t)(brow + wr * 128 + fr) * NB + fg * 16;
  const char* pb = (const char*)emb + (size_t)(bcol + wc * 64 + fr) * NB + fg * 16;

  #pragma unroll
  for (int kk = 0; kk < 16; kk++) {
    bf16x8 aF[8], bF[4];
    #pragma unroll
    for (int m = 0; m < 8; m++)
      aF[m] = *(const bf16x8*)(pa + (size_t)m * 16 * NB + kk * 64);
    #pragma unroll
    for (int n = 0; n < 4; n++)
      bF[n] = *(const bf16x8*)(pb + (size_t)n * 16 * NB + kk * 64);
    #pragma unroll
    for (int m = 0; m < 8; m++)
      #pragma unroll
      for (int n = 0; n < 4; n++)
        acc[m][n] = __builtin_amdgcn_mfma_f32_16x16x32_bf16(aF[m], bF[n], acc[m][n], 0, 0, 0);
  }

  __syncthreads();   // ids visible; epilogue LDS ready

  float* ps = part + (size_t)tbid * SLOT;   // [side][3 vals][256]

  // ---- epilogue: per-element masks; per-wave row partials into LDS ----
  int cl = fr;
  int cgrp = fg;
  int cidv[4];
  #pragma unroll
  for (int n = 0; n < 4; n++) cidv[n] = cidL[wc * 64 + n * 16 + cl];
  float cd[4], cp[4], cm[4];
  #pragma unroll
  for (int n = 0; n < 4; n++) { cd[n] = 0.f; cp[n] = 0.f; cm[n] = 0.f; }

  #pragma unroll
  for (int m = 0; m < 8; m++) {
    #pragma unroll
    for (int r = 0; r < 4; r++) {
      int row_l = wr * 128 + m * 16 + cgrp * 4 + r;
      int i = brow + row_l;
      int idi = ridL[row_l];
      float dsum = 0.f, psum = 0.f, msum = 0.f;
      #pragma unroll
      for (int n = 0; n < 4; n++) {
        int col_l = wc * 64 + n * 16 + cl;
        int j = bcol + col_l;
        float sim = acc[m][n][r] * INV_T;
        bool live = (!diag) || (i != j);
        if (live) {
          float e = __expf(sim);
          float hinge = fmaxf(sim + MARGIN_V, 0.f);
          bool same = (idi == cidv[n]);
          float psv = same ? sim : 0.f;
          float msv = same ? 0.f : hinge;
          dsum += e; psum += psv; msum += msv;
          if (!diag) { cd[n] += e; cp[n] += psv; cm[n] += msv; }
        }
      }
      #pragma unroll
      for (int s = 1; s < 16; s <<= 1) {
        dsum += __shfl_xor(dsum, s);
        psum += __shfl_xor(psum, s);
        msum += __shfl_xor(msum, s);
      }
      if (cl == 0) {            // per-wave slice: rps[w][row within 128]
        int o = w * 128 + (row_l & 127);
        rpd[o] = dsum; rpp[o] = psum; rpm[o] = msum;
      }
    }
  }

  if (!diag) {
    // col partials: shfl-combine the 4 row-groups within the wave, park in LDS
    #pragma unroll
    for (int n = 0; n < 4; n++) {
      float d = cd[n], p = cp[n], mm = cm[n];
      d += __shfl_xor(d, 16); d += __shfl_xor(d, 32);
      p += __shfl_xor(p, 16); p += __shfl_xor(p, 32);
      mm += __shfl_xor(mm, 16); mm += __shfl_xor(mm, 32);
      if (l < 16) {
        int o = ((w * 4 + n) * 16 + cl) * 3;
        cps[o] = d; cps[o + 1] = p; cps[o + 2] = mm;
      }
    }
  }
  __syncthreads();

  // row side: sum the 4 wc-wave slices, coalesced store
  if (t < 256) {
    int b0 = (t >> 7) * 512 + (t & 127);   // wr block base in rps
    float d = rpd[b0] + rpd[b0 + 128] + rpd[b0 + 256] + rpd[b0 + 384];
    float p = rpp[b0] + rpp[b0 + 128] + rpp[b0 + 256] + rpp[b0 + 384];
    float mm = rpm[b0] + rpm[b0 + 128] + rpm[b0 + 256] + rpm[b0 + 384];
    ps[t] = d; ps[256 + t] = p; ps[512 + t] = mm;
  }
  // col side: combine wr=0/wr=1 wave pairs, store (non-diag only; k_reduce
  // never reads the diag col side)
  if (!diag && wr == 0 && l < 16) {
    #pragma unroll
    for (int n = 0; n < 4; n++) {
      int o0 = ((w * 4 + n) * 16 + cl) * 3;
      int o1 = (((w + 4) * 4 + n) * 16 + cl) * 3;
      int col_l = wc * 64 + n * 16 + cl;
      ps[768 + col_l] = cps[o0] + cps[o1];
      ps[768 + 256 + col_l] = cps[o0 + 1] + cps[o1 + 1];
      ps[768 + 512 + col_l] = cps[o0 + 2] + cps[o1 + 2];
    }
  }
}

// ---- Kernel 3: reduce partials + per-row loss + per-block partial sum ----
__global__ __launch_bounds__(256) void k_reduce(
    const float* __restrict__ part, const int* __restrict__ mids,
    float* __restrict__ blockout) {
  __shared__ int hist[256];
  __shared__ float reds[256];
  __shared__ int redc[256];
  int t = threadIdx.x;
  hist[t] = 0;
  __syncthreads();
  for (int i = t; i < M_ROWS; i += 256) atomicAdd(&hist[mids[i]], 1);
  __syncthreads();

  int p = blockIdx.x;                       // panel 0..27
  int i = p * 256 + t;                      // row 0..7167
  float d = 0.f, pp = 0.f, mm = 0.f;
  int base = p * TILES2 - p * (p - 1) / 2;  // tbid(p, p)
  for (int yy = p; yy < TILES2; yy++) {     // row-side from tiles (p, yy)
    const float* s = part + (size_t)(base + yy - p) * SLOT;
    d += s[t]; pp += s[256 + t]; mm += s[512 + t];
  }
  for (int xx = 0; xx < p; xx++) {          // col-side from tiles (xx, p)
    int b = xx * TILES2 - xx * (xx - 1) / 2 + (p - xx);
    const float* s = part + (size_t)b * SLOT + 768;
    d += s[t]; pp += s[256 + t]; mm += s[512 + t];
  }

  int vmid; bool sh = false;
  if (i < TEXT_OFF) vmid = mids[i];
  else if (i < SHUF_OFF) vmid = mids[(i - TEXT_OFF) / 3];
  else { vmid = mids[(i - SHUF_OFF) / 3]; sh = true; }
  int c = hist[vmid];
  int npos = sh ? (3 * c - 1) : (4 * c - 1);
  int nneg = N_TOT - 1 - npos;
  float val = 0.f; int cnt = 0;
  if (npos > 0 && nneg > 0) {
    val = logf(d) - pp / (float)(npos > 1 ? npos : 1) + mm / (float)(nneg > 1 ? nneg : 1);
    cnt = 1;
  }
  reds[t] = val; redc[t] = cnt;
  __syncthreads();
  for (int s2 = 128; s2 > 0; s2 >>= 1) {
    if (t < s2) { reds[t] += reds[t + s2]; redc[t] += redc[t + s2]; }
    __syncthreads();
  }
  if (t == 0) { blockout[p * 2] = reds[0]; blockout[p * 2 + 1] = (float)redc[0]; }
}

// ---------------- Kernel 4: final scalar ----------------
__global__ __launch_bounds__(64) void k_final(
    const float* __restrict__ blockout, float* __restrict__ out) {
  int t = threadIdx.x;
  float s = 0.f, c = 0.f;
  if (t < TILES2) { s = blockout[t * 2]; c = blockout[t * 2 + 1]; }
  #pragma unroll
  for (int m = 32; m > 0; m >>= 1) { s += __shfl_down(s, m); c += __shfl_down(c, m); }
  if (t == 0) out[0] = (c > 0.f) ? s / c : 0.f;
}

// ---------------- Launch ----------------
extern "C" void kernel_launch(void* const* d_in, const int* in_sizes, int n_in,
                              void* d_out, int out_size, void* d_ws, size_t ws_size,
                              hipStream_t stream) {
  const float* motion = (const float*)d_in[0];
  const float* text   = (const float*)d_in[1];
  const float* shuf   = (const float*)d_in[2];
  const int*   mids   = (const int*)d_in[3];

  char* ws = (char*)d_ws;
  ushort* emb = (ushort*)ws;                                  // 7,340,032 B
  int* ids    = (int*)(ws + (size_t)N_TOT * DIM * 2);         // 28,672 B
  float* blockout = (float*)(ws + 7368704);                   // 28*2 floats
  float* part = (float*)(ws + 7454720);                       // 406*1536*4 = 2,494,464 B

  k_normalize<<<N_TOT / 4, 256, 0, stream>>>(motion, text, shuf, mids, emb, ids);
  k_gemm_loss<<<NBLK2, 512, 0, stream>>>(emb, ids, part);
  k_reduce<<<TILES2, 256, 0, stream>>>(part, mids, blockout);
  k_final<<<1, 64, 0, stream>>>(blockout, (float*)d_out);
}

// Round 10
// 74.420 us; speedup vs baseline: 1.8858x; 1.8858x over previous
//
#include <hip/hip_runtime.h>

#define M_ROWS 1024
#define DIM 512
#define NB 1024              // row bytes = DIM*2
#define N_TOT 7168           // M + 2*M*C
#define TEXT_OFF 1024
#define SHUF_OFF 4096
#define INV_T (1.0f/0.07f)
#define MARGIN_V 0.2f
#define TILES2 28            // N_TOT / 256
#define NBLK2 406            // 28*29/2 upper-triangular 256^2 tiles
#define SLOT 1536            // floats per partial slot: [2 sides][3 vals][256 rows]

typedef __attribute__((ext_vector_type(8))) short bf16x8;
typedef __attribute__((ext_vector_type(4))) float f32x4;

typedef const __attribute__((address_space(1))) unsigned int gas_uint;
typedef __attribute__((address_space(3))) unsigned int las_uint;

__device__ __forceinline__ void gload16(const void* g, void* l) {
  __builtin_amdgcn_global_load_lds((gas_uint*)g, (las_uint*)l, 16, 0, 0);
}

__device__ __forceinline__ ushort f2bf(float f) {
  unsigned u = __float_as_uint(f);
  u += 0x7fffu + ((u >> 16) & 1u);   // RTNE
  return (ushort)(u >> 16);
}

// DPP 16-lane row sum on the VALU pipe (no LDS/ds_bpermute traffic).
// After 4 stages, lane 15 of each 16-lane row holds the row's total.
__device__ __forceinline__ float dpp_sum16(float x) {
  float s = x;
  s += __int_as_float(__builtin_amdgcn_update_dpp(0, __float_as_int(s), 0x111, 0xF, 0xF, true)); // row_shr:1
  s += __int_as_float(__builtin_amdgcn_update_dpp(0, __float_as_int(s), 0x112, 0xF, 0xF, true)); // row_shr:2
  s += __int_as_float(__builtin_amdgcn_update_dpp(0, __float_as_int(s), 0x114, 0xF, 0xF, true)); // row_shr:4
  s += __int_as_float(__builtin_amdgcn_update_dpp(0, __float_as_int(s), 0x118, 0xF, 0xF, true)); // row_shr:8
  return s;
}

// ------- Kernel 1: normalize + cast bf16 + build ids -------
__global__ __launch_bounds__(256) void k_normalize(
    const float* __restrict__ motion, const float* __restrict__ text,
    const float* __restrict__ shuf, const int* __restrict__ mids,
    ushort* __restrict__ emb, int* __restrict__ ids) {
  int wave = threadIdx.x >> 6;
  int lane = threadIdx.x & 63;
  int row = blockIdx.x * 4 + wave;
  if (row >= N_TOT) return;
  const float* src;
  int id;
  if (row < TEXT_OFF) { src = motion + (size_t)row * DIM; id = mids[row]; }
  else if (row < SHUF_OFF) { int r = row - TEXT_OFF; src = text + (size_t)r * DIM; id = mids[r / 3]; }
  else { int r = row - SHUF_OFF; src = shuf + (size_t)r * DIM; id = mids[r / 3] + 100000; }

  float4 a = ((const float4*)src)[lane * 2];
  float4 b = ((const float4*)src)[lane * 2 + 1];
  float v0 = a.x + 1e-8f, v1 = a.y + 1e-8f, v2 = a.z + 1e-8f, v3 = a.w + 1e-8f;
  float v4 = b.x + 1e-8f, v5 = b.y + 1e-8f, v6 = b.z + 1e-8f, v7 = b.w + 1e-8f;
  float ss = v0*v0 + v1*v1 + v2*v2 + v3*v3 + v4*v4 + v5*v5 + v6*v6 + v7*v7;
  #pragma unroll
  for (int m = 1; m < 64; m <<= 1) ss += __shfl_xor(ss, m);
  float inv = 1.0f / fmaxf(sqrtf(ss), 1e-12f);

  uint w0 = (uint)f2bf(v0 * inv) | ((uint)f2bf(v1 * inv) << 16);
  uint w1 = (uint)f2bf(v2 * inv) | ((uint)f2bf(v3 * inv) << 16);
  uint w2 = (uint)f2bf(v4 * inv) | ((uint)f2bf(v5 * inv) << 16);
  uint w3 = (uint)f2bf(v6 * inv) | ((uint)f2bf(v7 * inv) << 16);
  uint4 pk; pk.x = w0; pk.y = w1; pk.z = w2; pk.w = w3;
  *((uint4*)(emb + (size_t)row * DIM + lane * 8)) = pk;
  if (lane == 0) ids[row] = id;
}

// -------- Kernel 2: symmetric fused A*A^T, 256^2 tiles, 8 waves --------
// R8 K-loop: triple-buffered LDS, 2-ahead prefetch, counted vmcnt(4), one
// barrier per step. Epilogue row-reduce moved OFF the LDS pipe: DPP adds
// on the VALU (the 384 ds_bpermute shuffles were sharing the LDS pipe with
// the K-loop's ds_read_b128 stream — the measured bottleneck).
__global__ __launch_bounds__(512, 2) void k_gemm_loss(
    const ushort* __restrict__ emb, const int* __restrict__ ids,
    float* __restrict__ part) {
  __shared__ ushort Asm[3][8192];   // [buf][256 rows x 32 bf16] = 16 KB per buf
  __shared__ ushort Bsm[3][8192];   // total static LDS = 96 KB

  // bijective XCD-chunked swizzle: nwg=406, q=50, r=6
  int orig = blockIdx.x;
  int xcd = orig & 7;
  int idx = orig >> 3;
  int bid = (xcd < 6 ? xcd * 51 : 306 + (xcd - 6) * 50) + idx;

  // triangular tile decode: bid -> (x, y), x <= y
  int x = 0;
  while (bid >= TILES2 - x) { bid -= TILES2 - x; x++; }
  int y = x + bid;
  bool diag = (x == y);
  int brow = x * 256, bcol = y * 256;
  int tbid = x * TILES2 - x * (x - 1) / 2 + (y - x);   // linear triangular id

  int t = threadIdx.x;
  int l = t & 63;
  int w = t >> 6;
  int wr = w >> 2;           // wave row 0..1  -> 128 output rows
  int wc = w & 3;            // wave col 0..3  -> 64 output cols
  int fr = l & 15;
  int fg = l >> 4;           // 0..3

  // staging: lane l stages row (w*16 + l>>2) of each 128-row chunk,
  // source col pre-swizzled so linear LDS dest holds the swizzled layout
  int srow = w * 16 + (l >> 2);
  int scol = ((l & 3) ^ ((l >> 3) & 3)) * 16;          // swizzled source byte col
  const char* gA = (const char*)emb + (size_t)(brow + srow) * NB + scol;
  const char* gB = (const char*)emb + (size_t)(bcol + srow) * NB + scol;
  int ldso = w * 512;

  f32x4 acc[8][4];
  #pragma unroll
  for (int m = 0; m < 8; m++)
    #pragma unroll
    for (int n = 0; n < 4; n++)
      acc[m][n] = (f32x4){0.f, 0.f, 0.f, 0.f};

  // swizzled ds_read column offset (ushorts): phys colgroup = fg ^ ((row>>1)&3)
  int swz = (fg ^ ((fr >> 1) & 3)) * 8;

#define STAGE(T) do { \
    const int _b = (T) % 3; const int _kb = (T) * 64; \
    gload16(gA + _kb,          &Asm[_b][ldso]); \
    gload16(gA + 131072 + _kb, &Asm[_b][4096 + ldso]); \
    gload16(gB + _kb,          &Bsm[_b][ldso]); \
    gload16(gB + 131072 + _kb, &Bsm[_b][4096 + ldso]); \
  } while (0)

  // prologue: tiles 0 and 1 in flight; wait tile 0 only
  STAGE(0);
  STAGE(1);
  asm volatile("s_waitcnt vmcnt(4)" ::: "memory");
  __builtin_amdgcn_s_barrier();

  #pragma unroll
  for (int tt = 0; tt < 16; tt++) {
    if (tt + 2 < 16) STAGE(tt + 2);   // disjoint buffer: no read conflict
    const int _b = tt % 3;
    const ushort* Ab = &Asm[_b][(wr * 128 + fr) * 32 + swz];
    const ushort* Bb = &Bsm[_b][(wc * 64 + fr) * 32 + swz];
    bf16x8 aF[8], bF[4];
    #pragma unroll
    for (int m = 0; m < 8; m++) aF[m] = *(const bf16x8*)(Ab + m * 512);
    #pragma unroll
    for (int n = 0; n < 4; n++) bF[n] = *(const bf16x8*)(Bb + n * 512);
    __builtin_amdgcn_s_setprio(1);
    #pragma unroll
    for (int m = 0; m < 8; m++)
      #pragma unroll
      for (int n = 0; n < 4; n++)
        acc[m][n] = __builtin_amdgcn_mfma_f32_16x16x32_bf16(aF[m], bF[n], acc[m][n], 0, 0, 0);
    __builtin_amdgcn_s_setprio(0);
    if (tt < 14) {
      // outstanding: tile tt+1 (4) + tile tt+2 (4); retire tile tt+1 only
      asm volatile("s_waitcnt vmcnt(4)" ::: "memory");
      __builtin_amdgcn_s_barrier();
    } else if (tt == 14) {
      asm volatile("s_waitcnt vmcnt(0)" ::: "memory");
      __builtin_amdgcn_s_barrier();
    }
  }
#undef STAGE

  // ---- reuse LDS after K-loop ----
  // Asm[0..1]: row-partial exchange rps[8 waves][128 rows] x 3 vals (12 KB)
  // Bsm[0]: col-partial exchange (6 KB); Bsm[1]: rid/cid (2 KB)
  // ids go to Bsm[1] (not touched at step 15, whose buffer is index 0) —
  // safe to write before the barrier; rpd aliases Asm[0] (step-15 read
  // buffer) so rpd writes happen only after the barrier below.
  float* rpd = (float*)&Asm[0][0];
  float* rpp = rpd + 1024;
  float* rpm = rpp + 1024;
  float* cps = (float*)&Bsm[0][0];
  int* ridL = (int*)&Bsm[1][0];
  int* cidL = ridL + 256;
  if (t < 256) ridL[t] = ids[brow + t];
  else cidL[t - 256] = ids[bcol + (t - 256)];
  __syncthreads();

  float* ps = part + (size_t)tbid * SLOT;   // [side][3 vals][256]

  // ---- epilogue: per-element masks; DPP row-reduce (VALU pipe) ----
  int cl = fr;
  int cgrp = fg;
  int cidv[4];
  #pragma unroll
  for (int n = 0; n < 4; n++) cidv[n] = cidL[wc * 64 + n * 16 + cl];
  float cd[4], cp[4], cm[4];
  #pragma unroll
  for (int n = 0; n < 4; n++) { cd[n] = 0.f; cp[n] = 0.f; cm[n] = 0.f; }

  #pragma unroll
  for (int m = 0; m < 8; m++) {
    #pragma unroll
    for (int r = 0; r < 4; r++) {
      int row_l = wr * 128 + m * 16 + cgrp * 4 + r;
      int i = brow + row_l;
      int idi = ridL[row_l];
      float dsum = 0.f, psum = 0.f, msum = 0.f;
      #pragma unroll
      for (int n = 0; n < 4; n++) {
        int col_l = wc * 64 + n * 16 + cl;
        int j = bcol + col_l;
        float sim = acc[m][n][r] * INV_T;
        bool live = (!diag) || (i != j);
        if (live) {
          float e = __expf(sim);
          float hinge = fmaxf(sim + MARGIN_V, 0.f);
          bool same = (idi == cidv[n]);
          float psv = same ? sim : 0.f;
          float msv = same ? 0.f : hinge;
          dsum += e; psum += psv; msum += msv;
          if (!diag) { cd[n] += e; cp[n] += psv; cm[n] += msv; }
        }
      }
      // 16-lane row sums on the VALU (DPP); totals land in lane cl==15
      dsum = dpp_sum16(dsum);
      psum = dpp_sum16(psum);
      msum = dpp_sum16(msum);
      if (cl == 15) {           // per-wave slice: rps[w][row within 128]
        int o = w * 128 + (row_l & 127);
        rpd[o] = dsum; rpp[o] = psum; rpm[o] = msum;
      }
    }
  }

  if (!diag) {
    // col partials: shfl-combine the 4 row-groups within the wave, park in LDS
    #pragma unroll
    for (int n = 0; n < 4; n++) {
      float d = cd[n], p = cp[n], mm = cm[n];
      d += __shfl_xor(d, 16); d += __shfl_xor(d, 32);
      p += __shfl_xor(p, 16); p += __shfl_xor(p, 32);
      mm += __shfl_xor(mm, 16); mm += __shfl_xor(mm, 32);
      if (l < 16) {
        int o = ((w * 4 + n) * 16 + cl) * 3;
        cps[o] = d; cps[o + 1] = p; cps[o + 2] = mm;
      }
    }
  }
  __syncthreads();

  // row side: sum the 4 wc-wave slices, coalesced store
  if (t < 256) {
    int b0 = (t >> 7) * 512 + (t & 127);   // wr block base in rps
    float d = rpd[b0] + rpd[b0 + 128] + rpd[b0 + 256] + rpd[b0 + 384];
    float p = rpp[b0] + rpp[b0 + 128] + rpp[b0 + 256] + rpp[b0 + 384];
    float mm = rpm[b0] + rpm[b0 + 128] + rpm[b0 + 256] + rpm[b0 + 384];
    ps[t] = d; ps[256 + t] = p; ps[512 + t] = mm;
  }
  // col side: combine wr=0/wr=1 wave pairs, store (non-diag only; k_reduce
  // never reads the diag col side)
  if (!diag && wr == 0 && l < 16) {
    #pragma unroll
    for (int n = 0; n < 4; n++) {
      int o0 = ((w * 4 + n) * 16 + cl) * 3;
      int o1 = (((w + 4) * 4 + n) * 16 + cl) * 3;
      int col_l = wc * 64 + n * 16 + cl;
      ps[768 + col_l] = cps[o0] + cps[o1];
      ps[768 + 256 + col_l] = cps[o0 + 1] + cps[o1 + 1];
      ps[768 + 512 + col_l] = cps[o0 + 2] + cps[o1 + 2];
    }
  }
}

// ---- Kernel 3: reduce partials + per-row loss + per-block partial sum ----
__global__ __launch_bounds__(256) void k_reduce(
    const float* __restrict__ part, const int* __restrict__ mids,
    float* __restrict__ blockout) {
  __shared__ int hist[256];
  __shared__ float reds[256];
  __shared__ int redc[256];
  int t = threadIdx.x;
  hist[t] = 0;
  __syncthreads();
  for (int i = t; i < M_ROWS; i += 256) atomicAdd(&hist[mids[i]], 1);
  __syncthreads();

  int p = blockIdx.x;                       // panel 0..27
  int i = p * 256 + t;                      // row 0..7167
  float d = 0.f, pp = 0.f, mm = 0.f;
  int base = p * TILES2 - p * (p - 1) / 2;  // tbid(p, p)
  for (int yy = p; yy < TILES2; yy++) {     // row-side from tiles (p, yy)
    const float* s = part + (size_t)(base + yy - p) * SLOT;
    d += s[t]; pp += s[256 + t]; mm += s[512 + t];
  }
  for (int xx = 0; xx < p; xx++) {          // col-side from tiles (xx, p)
    int b = xx * TILES2 - xx * (xx - 1) / 2 + (p - xx);
    const float* s = part + (size_t)b * SLOT + 768;
    d += s[t]; pp += s[256 + t]; mm += s[512 + t];
  }

  int vmid; bool sh = false;
  if (i < TEXT_OFF) vmid = mids[i];
  else if (i < SHUF_OFF) vmid = mids[(i - TEXT_OFF) / 3];
  else { vmid = mids[(i - SHUF_OFF) / 3]; sh = true; }
  int c = hist[vmid];
  int npos = sh ? (3 * c - 1) : (4 * c - 1);
  int nneg = N_TOT - 1 - npos;
  float val = 0.f; int cnt = 0;
  if (npos > 0 && nneg > 0) {
    val = logf(d) - pp / (float)(npos > 1 ? npos : 1) + mm / (float)(nneg > 1 ? nneg : 1);
    cnt = 1;
  }
  reds[t] = val; redc[t] = cnt;
  __syncthreads();
  for (int s2 = 128; s2 > 0; s2 >>= 1) {
    if (t < s2) { reds[t] += reds[t + s2]; redc[t] += redc[t + s2]; }
    __syncthreads();
  }
  if (t == 0) { blockout[p * 2] = reds[0]; blockout[p * 2 + 1] = (float)redc[0]; }
}

// ---------------- Kernel 4: final scalar ----------------
__global__ __launch_bounds__(64) void k_final(
    const float* __restrict__ blockout, float* __restrict__ out) {
  int t = threadIdx.x;
  float s = 0.f, c = 0.f;
  if (t < TILES2) { s = blockout[t * 2]; c = blockout[t * 2 + 1]; }
  #pragma unroll
  for (int m = 32; m > 0; m >>= 1) { s += __shfl_down(s, m); c += __shfl_down(c, m); }
  if (t == 0) out[0] = (c > 0.f) ? s / c : 0.f;
}

// ---------------- Launch ----------------
extern "C" void kernel_launch(void* const* d_in, const int* in_sizes, int n_in,
                              void* d_out, int out_size, void* d_ws, size_t ws_size,
                              hipStream_t stream) {
  const float* motion = (const float*)d_in[0];
  const float* text   = (const float*)d_in[1];
  const float* shuf   = (const float*)d_in[2];
  const int*   mids   = (const int*)d_in[3];

  char* ws = (char*)d_ws;
  ushort* emb = (ushort*)ws;                                  // 7,340,032 B
  int* ids    = (int*)(ws + (size_t)N_TOT * DIM * 2);         // 28,672 B
  float* blockout = (float*)(ws + 7368704);                   // 28*2 floats
  float* part = (float*)(ws + 7454720);                       // 406*1536*4 = 2,494,464 B

  k_normalize<<<N_TOT / 4, 256, 0, stream>>>(motion, text, shuf, mids, emb, ids);
  k_gemm_loss<<<NBLK2, 512, 0, stream>>>(emb, ids, part);
  k_reduce<<<TILES2, 256, 0, stream>>>(part, mids, blockout);
  k_final<<<1, 64, 0, stream>>>(blockout, (float*)d_out);
}